// Round 3
// baseline (1617.728 us; speedup 1.0000x reference)
//
#include <hip/hip_runtime.h>
#include <hip/hip_bf16.h>
#include <hip/hip_cooperative_groups.h>
#include <math.h>

// Observer recurrence -> LTI Markov-parameter convolution, meet-in-the-middle.
//   A' = A - L*C, K = [B - L*D | L | h0]
//   f_m = C A'^m K = (A'^T^i C^T) . (A'^j K),  i = min(m,31), j = m - i
//   v-chain: v_{i+1} = A'^T v_i (depth 31, split-bf16 seeds for i<12)
//   W-chain: W_{j+1} = A' W_j  (depth 32, plain bf16 — only feeds m>=31 terms)
//   y_t = f_t[9] + D u_t + sum_j f_j . z_{t-1-j}; out = 3*tanh(y)
// J=64 truncation (rho~0.9 -> 0.9^64 ~ 1.2e-3 tail).
// Both chains advance in ONE persistent cooperative kernel (32 grid.sync's)
// so A'/A'^T (96 MB) stay L3-resident and per-launch overhead vanishes.

namespace cg = cooperative_groups;

constexpr int NDIM  = 4096;
constexpr int NC    = 10;         // live columns of K/W
constexpr int SLAB  = 16 * 4096;  // padded 16-col col-major slab (elements)
constexpr int JT    = 64;         // truncation length
constexpr int SEEDS = 12;         // split-precision seed steps (v-chain)
constexpr int ITERS = 32;         // chain iterations (v depth 31, W depth 32)

typedef float f32x4  __attribute__((ext_vector_type(4)));
typedef short short8 __attribute__((ext_vector_type(8)));

// ---------- build A' hi (row-major) + A'^T hi/lo (tiled transpose) ----------
__global__ __launch_bounds__(256) void k_build_a(
        const float* __restrict__ A, const float* __restrict__ C,
        const float* __restrict__ L,
        __hip_bfloat16* __restrict__ Ah, __hip_bfloat16* __restrict__ AhT,
        __hip_bfloat16* __restrict__ AlT) {
    __shared__ unsigned short hiT[64][68]; // [col-local][row-local], 8B-aligned rows
    __shared__ unsigned short loT[64][68];
    const int bi = blockIdx.x >> 6, bj = blockIdx.x & 63;
    const int i0 = bi << 6, j0 = bj << 6;
    const int r  = threadIdx.x >> 4;
    const int c4 = (threadIdx.x & 15) << 2;
    #pragma unroll
    for (int p = 0; p < 4; ++p) {
        const int il = r + (p << 4);
        const int i  = i0 + il;
        const float4 a = *(const float4*)(A + (size_t)i * NDIM + j0 + c4);
        const float Li = L[i];
        float v[4] = { a.x - Li * C[j0 + c4 + 0], a.y - Li * C[j0 + c4 + 1],
                       a.z - Li * C[j0 + c4 + 2], a.w - Li * C[j0 + c4 + 3] };
        union { ushort4 u4; __hip_bfloat16 h[4]; } hi, lo;
        #pragma unroll
        for (int s = 0; s < 4; ++s) {
            hi.h[s] = __float2bfloat16(v[s]);
            lo.h[s] = __float2bfloat16(v[s] - __bfloat162float(hi.h[s]));
        }
        *(ushort4*)((unsigned short*)Ah + (size_t)i * NDIM + j0 + c4) = hi.u4;
        #pragma unroll
        for (int s = 0; s < 4; ++s) {
            hiT[c4 + s][il] = ((unsigned short*)&hi.u4)[s];
            loT[c4 + s][il] = ((unsigned short*)&lo.u4)[s];
        }
    }
    __syncthreads();
    #pragma unroll
    for (int p = 0; p < 4; ++p) {
        const int jl = r + (p << 4);
        ushort4 h = *(ushort4*)&hiT[jl][c4];
        ushort4 l = *(ushort4*)&loT[jl][c4];
        *(ushort4*)((unsigned short*)AhT + (size_t)(j0 + jl) * NDIM + i0 + c4) = h;
        *(ushort4*)((unsigned short*)AlT + (size_t)(j0 + jl) * NDIM + i0 + c4) = l;
    }
}

// ---------- W0 = K = [B-L*D | L | ones | 0-pad], col-major fp32 + bf16 ----------
__global__ __launch_bounds__(256) void k_build_w0(
        const float* __restrict__ Bm, const float* __restrict__ Dm,
        const float* __restrict__ L, float* __restrict__ Wf,
        __hip_bfloat16* __restrict__ Wh) {
    int k = blockIdx.x * blockDim.x + threadIdx.x; // < 4096
    float Lk = L[k];
    float col[16];
    #pragma unroll
    for (int c = 0; c < 8; ++c) col[c] = Bm[k * 8 + c] - Lk * Dm[c];
    col[8] = Lk; col[9] = 1.0f;
    #pragma unroll
    for (int c = 10; c < 16; ++c) col[c] = 0.0f;
    #pragma unroll
    for (int c = 0; c < 16; ++c) {
        Wf[c * NDIM + k] = col[c];
        Wh[c * NDIM + k] = __float2bfloat16(col[c]);
    }
}

// ---------- v0 = C^T in slab col 0, fp32 + split bf16 ----------
__global__ __launch_bounds__(256) void k_build_v0(
        const float* __restrict__ C, float* __restrict__ Vf,
        __hip_bfloat16* __restrict__ Vh, __hip_bfloat16* __restrict__ Vl) {
    int k = blockIdx.x * blockDim.x + threadIdx.x; // < 4096
    #pragma unroll
    for (int c = 0; c < 16; ++c) {
        float val = (c == 0) ? C[k] : 0.0f;
        Vf[c * NDIM + k] = val;
        __hip_bfloat16 h = __float2bfloat16(val);
        Vh[c * NDIM + k] = h;
        Vl[c * NDIM + k] = __float2bfloat16(val - __bfloat162float(h));
    }
}

// ---------- one chain step for this block's 16 output rows ----------
// A-frag: lane = m + 16q holds M[row m][k=q*8+j]; B-frag same with col role.
// D: col = lane&15, row = (lane>>4)*4 + i (m89-verified; round-2 validated).
__device__ __forceinline__ void step_tile(
        const __hip_bfloat16* __restrict__ Mh, const __hip_bfloat16* __restrict__ Ml,
        const __hip_bfloat16* __restrict__ Xh, const __hip_bfloat16* __restrict__ Xl,
        float* __restrict__ Yf, __hip_bfloat16* __restrict__ Yh,
        __hip_bfloat16* __restrict__ Yl,
        f32x4* red, int row0, int tid, bool split, bool writeLo) {
    const int lane = tid & 63, wave = tid >> 6;
    const int mr = lane & 15, q = lane >> 4;
    const size_t aBase = (((size_t)(row0 + mr) * NDIM + wave * 512) >> 3) + q;
    const size_t wBase = (((size_t)mr * NDIM + wave * 512) >> 3) + q;
    const short8* mh8 = (const short8*)Mh + aBase;
    const short8* xh8 = (const short8*)Xh + wBase;
    f32x4 acc0 = {0, 0, 0, 0}, acc1 = {0, 0, 0, 0};
    if (split) {
        const short8* ml8 = (const short8*)Ml + aBase;
        const short8* xl8 = (const short8*)Xl + wBase;
        #pragma unroll 4
        for (int i = 0; i < 16; ++i) {
            short8 a = mh8[i * 4], b = xh8[i * 4];
            short8 al = ml8[i * 4], bl = xl8[i * 4];
            acc0 = __builtin_amdgcn_mfma_f32_16x16x32_bf16(a, b, acc0, 0, 0, 0);
            acc1 = __builtin_amdgcn_mfma_f32_16x16x32_bf16(a, bl, acc1, 0, 0, 0);
            acc0 = __builtin_amdgcn_mfma_f32_16x16x32_bf16(al, b, acc0, 0, 0, 0);
        }
    } else {
        #pragma unroll 8
        for (int i = 0; i < 16; i += 2) {
            acc0 = __builtin_amdgcn_mfma_f32_16x16x32_bf16(mh8[i * 4], xh8[i * 4], acc0, 0, 0, 0);
            acc1 = __builtin_amdgcn_mfma_f32_16x16x32_bf16(mh8[i * 4 + 4], xh8[i * 4 + 4], acc1, 0, 0, 0);
        }
    }
    red[wave * 64 + lane] = acc0 + acc1;
    __syncthreads();
    if (tid < 256) {
        const int l = tid & 63, i = tid >> 6;
        float v = 0.0f;
        #pragma unroll
        for (int w = 0; w < 8; ++w) v += red[w * 64 + l][i];
        const int col = l & 15;
        const int row = row0 + ((l >> 4) << 2) + i;
        Yf[col * NDIM + row] = v;
        __hip_bfloat16 h = __float2bfloat16(v);
        Yh[col * NDIM + row] = h;
        if (writeLo) Yl[col * NDIM + row] = __float2bfloat16(v - __bfloat162float(h));
    }
    __syncthreads(); // red reused by next phase
}

// ---------- persistent cooperative chain: both Krylov chains, 32 iters ----------
__global__ __launch_bounds__(512, 1) void k_chain(
        const __hip_bfloat16* __restrict__ Ah, const __hip_bfloat16* __restrict__ AhT,
        const __hip_bfloat16* __restrict__ AlT,
        __hip_bfloat16* __restrict__ Wh, float* __restrict__ Wf,
        __hip_bfloat16* __restrict__ Vh, __hip_bfloat16* __restrict__ Vl,
        float* __restrict__ Vf) {
    cg::grid_group grid = cg::this_grid();
    __shared__ f32x4 red[512];
    const int tid  = threadIdx.x;
    const int row0 = blockIdx.x * 16;
    for (int it = 0; it < ITERS; ++it) {
        if (it < ITERS - 1) { // v-chain: v_{it+1} = A'^T v_it (depth 31)
            const bool sp = (it < SEEDS);
            step_tile(AhT, AlT,
                      Vh + (size_t)it * SLAB, Vl + (size_t)it * SLAB,
                      Vf + (size_t)(it + 1) * SLAB, Vh + (size_t)(it + 1) * SLAB,
                      Vl + (size_t)(it + 1) * SLAB,
                      red, row0, tid, sp, it + 1 <= SEEDS);
        }
        // W-chain: W_{it+1} = A' W_it (depth 32, plain bf16)
        step_tile(Ah, nullptr,
                  Wh + (size_t)it * SLAB, nullptr,
                  Wf + (size_t)(it + 1) * SLAB, Wh + (size_t)(it + 1) * SLAB,
                  nullptr, red, row0, tid, false, false);
        grid.sync();
    }
}

// ---------- F_m = v_i . W_j  (i = min(m,31), j = m-i), fp32 ----------
__global__ __launch_bounds__(256) void k_fbatch(
        const float* __restrict__ Vf, const float* __restrict__ Wf,
        float* __restrict__ F) {
    const int m = blockIdx.x;
    const int i = (m < ITERS - 1) ? m : (ITERS - 1);
    const int j = m - i;
    const float* v = Vf + (size_t)i * SLAB; // col 0 = v_i
    const float* W = Wf + (size_t)j * SLAB;
    const int tid = threadIdx.x, lane = tid & 63, wave = tid >> 6;
    float acc[NC] = {};
    for (int k = tid; k < NDIM; k += 256) {
        float vk = v[k];
        #pragma unroll
        for (int c = 0; c < NC; ++c) acc[c] += vk * W[c * NDIM + k];
    }
    __shared__ float red[4][NC];
    #pragma unroll
    for (int c = 0; c < NC; ++c) {
        float s = acc[c];
        #pragma unroll
        for (int off = 32; off > 0; off >>= 1) s += __shfl_down(s, off);
        if (lane == 0) red[wave][c] = s;
    }
    __syncthreads();
    if (tid < NC) F[m * NC + tid] = red[0][tid] + red[1][tid] + red[2][tid] + red[3][tid];
}

// ---------- causal convolution + tanh epilogue ----------
__global__ __launch_bounds__(256) void k_conv(
        const float* __restrict__ F, const float* __restrict__ u,
        const float* __restrict__ yobs, const float* __restrict__ Dm,
        float* __restrict__ out) {
    __shared__ float Fl[JT * NC];          // 640 floats
    __shared__ float zw[(JT + 256) * 9];   // 2880 floats, zero-padded window
    const int tid = threadIdx.x;
    const int t0  = blockIdx.x * 256;
    for (int idx = tid; idx < JT * NC; idx += 256) Fl[idx] = F[idx];
    for (int idx = tid; idx < (JT + 256) * 9; idx += 256) {
        int k = idx / 9, c = idx - k * 9;
        int s = t0 - JT + k;
        float v = 0.0f;
        if (s >= 0 && s < NDIM) v = (c < 8) ? u[c * NDIM + s] : yobs[s];
        zw[idx] = v;
    }
    __syncthreads();
    const int t = t0 + tid;
    float y = (t < JT) ? Fl[t * NC + 9] : 0.0f; // C A'^t h0 term (truncated)
    #pragma unroll
    for (int c = 0; c < 8; ++c) y += Dm[c] * u[c * NDIM + t];
    for (int j = 0; j < JT; ++j) { // s = t-1-j; s<0 hits zero pad
        const float* fj = Fl + j * NC;
        const float* zz = zw + (tid + JT - 1 - j) * 9;
        float p = 0.0f;
        #pragma unroll
        for (int c = 0; c < 9; ++c) p += fj[c] * zz[c];
        y += p;
    }
    out[t] = 3.0f * tanhf(y);
}

extern "C" void kernel_launch(void* const* d_in, const int* in_sizes, int n_in,
                              void* d_out, int out_size, void* d_ws, size_t ws_size,
                              hipStream_t stream) {
    const float* u    = (const float*)d_in[0];
    const float* yobs = (const float*)d_in[1];
    const float* A    = (const float*)d_in[2];
    const float* Bm   = (const float*)d_in[3];
    const float* C    = (const float*)d_in[4];
    const float* Dm   = (const float*)d_in[5];
    const float* L    = (const float*)d_in[6];
    float* out = (float*)d_out;

    // workspace layout (~131 MB; round-1 proved >=176 MB available)
    char* ws = (char*)d_ws;
    __hip_bfloat16* Ah  = (__hip_bfloat16*)ws;                       // 32 MB
    __hip_bfloat16* AhT = (__hip_bfloat16*)(ws + 33554432ull);       // 32 MB
    __hip_bfloat16* AlT = (__hip_bfloat16*)(ws + 67108864ull);       // 32 MB
    __hip_bfloat16* Wh  = (__hip_bfloat16*)(ws + 100663296ull);      // 33*128 KB
    float*          Wf  = (float*)(ws + 104988672ull);               // 33*256 KB
    __hip_bfloat16* Vh  = (__hip_bfloat16*)(ws + 113639424ull);      // 32*128 KB
    __hip_bfloat16* Vl  = (__hip_bfloat16*)(ws + 117833728ull);      // 32*128 KB
    float*          Vf  = (float*)(ws + 122028032ull);               // 32*256 KB
    float*          F   = (float*)(ws + 130416640ull);               // 2.56 KB

    k_build_a<<<dim3(4096), dim3(256), 0, stream>>>(A, C, L, Ah, AhT, AlT);
    k_build_w0<<<dim3(16), dim3(256), 0, stream>>>(Bm, Dm, L, Wf, Wh);
    k_build_v0<<<dim3(16), dim3(256), 0, stream>>>(C, Vf, Vh, Vl);

    {
        const __hip_bfloat16 *pAh = Ah, *pAhT = AhT, *pAlT = AlT;
        __hip_bfloat16 *pWh = Wh, *pVh = Vh, *pVl = Vl;
        float *pWf = Wf, *pVf = Vf;
        void* args[] = {&pAh, &pAhT, &pAlT, &pWh, &pWf, &pVh, &pVl, &pVf};
        hipLaunchCooperativeKernel((const void*)k_chain, dim3(256), dim3(512),
                                   args, 0, stream);
    }

    k_fbatch<<<dim3(JT), dim3(256), 0, stream>>>(Vf, Wf, F);
    k_conv<<<dim3(16), dim3(256), 0, stream>>>(F, u, yobs, Dm, out);
}

// Round 4
// 1559.712 us; speedup vs baseline: 1.0372x; 1.0372x over previous
//
#include <hip/hip_runtime.h>
#include <hip/hip_bf16.h>
#include <hip/hip_cooperative_groups.h>
#include <math.h>

// Observer recurrence -> LTI Markov-parameter convolution, meet-in-the-middle.
//   A' = A - L*C, K = [B - L*D | L | h0]
//   f_m = C A'^m K = (A'^T^i C^T) . (A'^j K),  i = min(m,31), j = m - i
// v-chain packs v_hi (plane 0) and v_lo (plane 1) in one B operand:
//   one MFMA stream gives Ah*vh (col0) + Ah*vl (col1); seeds add AlT*v stream.
// Round-4 change vs round-3: batched register loads (8 frags/stream before
// MFMAs) for memory-level parallelism — round 3 was latency-bound (VGPR=64,
// ~5% HBM, 1.3% MFMA). __launch_bounds__(512,2) caps VGPR at 256.

namespace cg = cooperative_groups;

constexpr int NDIM  = 4096;
constexpr int NC    = 10;         // live columns of K/W
constexpr int SLAB  = 16 * 4096;  // padded 16-col col-major slab (elements)
constexpr int JT    = 64;         // truncation length
constexpr int SEEDS = 12;         // AlT-corrected seed steps (v-chain)
constexpr int ITERS = 32;         // chain iterations (v depth 31, W depth 32)

typedef float f32x4  __attribute__((ext_vector_type(4)));
typedef short short8 __attribute__((ext_vector_type(8)));

// ---------- build A' hi (row-major) + A'^T hi/lo (tiled transpose) ----------
__global__ __launch_bounds__(256) void k_build_a(
        const float* __restrict__ A, const float* __restrict__ C,
        const float* __restrict__ L,
        __hip_bfloat16* __restrict__ Ah, __hip_bfloat16* __restrict__ AhT,
        __hip_bfloat16* __restrict__ AlT) {
    __shared__ unsigned short hiT[64][68];
    __shared__ unsigned short loT[64][68];
    const int bi = blockIdx.x >> 6, bj = blockIdx.x & 63;
    const int i0 = bi << 6, j0 = bj << 6;
    const int r  = threadIdx.x >> 4;
    const int c4 = (threadIdx.x & 15) << 2;
    #pragma unroll
    for (int p = 0; p < 4; ++p) {
        const int il = r + (p << 4);
        const int i  = i0 + il;
        const float4 a = *(const float4*)(A + (size_t)i * NDIM + j0 + c4);
        const float Li = L[i];
        float v[4] = { a.x - Li * C[j0 + c4 + 0], a.y - Li * C[j0 + c4 + 1],
                       a.z - Li * C[j0 + c4 + 2], a.w - Li * C[j0 + c4 + 3] };
        union { ushort4 u4; __hip_bfloat16 h[4]; } hi, lo;
        #pragma unroll
        for (int s = 0; s < 4; ++s) {
            hi.h[s] = __float2bfloat16(v[s]);
            lo.h[s] = __float2bfloat16(v[s] - __bfloat162float(hi.h[s]));
        }
        *(ushort4*)((unsigned short*)Ah + (size_t)i * NDIM + j0 + c4) = hi.u4;
        #pragma unroll
        for (int s = 0; s < 4; ++s) {
            hiT[c4 + s][il] = ((unsigned short*)&hi.u4)[s];
            loT[c4 + s][il] = ((unsigned short*)&lo.u4)[s];
        }
    }
    __syncthreads();
    #pragma unroll
    for (int p = 0; p < 4; ++p) {
        const int jl = r + (p << 4);
        ushort4 h = *(ushort4*)&hiT[jl][c4];
        ushort4 l = *(ushort4*)&loT[jl][c4];
        *(ushort4*)((unsigned short*)AhT + (size_t)(j0 + jl) * NDIM + i0 + c4) = h;
        *(ushort4*)((unsigned short*)AlT + (size_t)(j0 + jl) * NDIM + i0 + c4) = l;
    }
}

// ---------- W0 = K = [B-L*D | L | ones | 0-pad], col-major fp32 + bf16 ----------
__global__ __launch_bounds__(256) void k_build_w0(
        const float* __restrict__ Bm, const float* __restrict__ Dm,
        const float* __restrict__ L, float* __restrict__ Wf,
        __hip_bfloat16* __restrict__ Wh) {
    int k = blockIdx.x * blockDim.x + threadIdx.x; // < 4096
    float Lk = L[k];
    float col[16];
    #pragma unroll
    for (int c = 0; c < 8; ++c) col[c] = Bm[k * 8 + c] - Lk * Dm[c];
    col[8] = Lk; col[9] = 1.0f;
    #pragma unroll
    for (int c = 10; c < 16; ++c) col[c] = 0.0f;
    #pragma unroll
    for (int c = 0; c < 16; ++c) {
        Wf[c * NDIM + k] = col[c];
        Wh[c * NDIM + k] = __float2bfloat16(col[c]);
    }
}

// ---------- v0: plane0 = hi(C^T), plane1 = lo(C^T), planes 2..15 = 0 ----------
__global__ __launch_bounds__(256) void k_build_v0(
        const float* __restrict__ C, float* __restrict__ Vf,
        __hip_bfloat16* __restrict__ Vh) {
    int k = blockIdx.x * blockDim.x + threadIdx.x; // < 4096
    float c = C[k];
    __hip_bfloat16 h = __float2bfloat16(c);
    Vf[k] = c;
    Vh[k] = h;
    Vh[NDIM + k] = __float2bfloat16(c - __bfloat162float(h));
    #pragma unroll
    for (int p = 2; p < 16; ++p) Vh[p * NDIM + k] = __float2bfloat16(0.0f);
}

// ---------- persistent cooperative chain: both Krylov chains, 32 iters ----------
// A-frag: lane = m + 16q holds M[row m][k=q*8+j]; B-frag col n = lane&15 reads
// plane n. D: col = lane&15, row = (lane>>4)*4 + i (validated rounds 2-3).
__global__ __launch_bounds__(512, 2) void k_chain(
        const __hip_bfloat16* __restrict__ Ah, const __hip_bfloat16* __restrict__ AhT,
        const __hip_bfloat16* __restrict__ AlT,
        __hip_bfloat16* __restrict__ Wh, float* __restrict__ Wf,
        __hip_bfloat16* __restrict__ Vh, float* __restrict__ Vf) {
    cg::grid_group grid = cg::this_grid();
    __shared__ f32x4 redV[512];
    __shared__ f32x4 redW[512];
    const int tid  = threadIdx.x;
    const int lane = tid & 63, wave = tid >> 6;
    const int mr   = lane & 15, q = lane >> 4;
    const int row0 = blockIdx.x * 16;
    const size_t aBase = (((size_t)(row0 + mr) * NDIM + wave * 512) >> 3) + q;
    const size_t wBase = (((size_t)mr * NDIM + wave * 512) >> 3) + q;
    const size_t slab8 = SLAB / 8;
    const short8* aT8 = (const short8*)AhT + aBase;
    const short8* aW8 = (const short8*)Ah  + aBase;
    const short8* aS8 = (const short8*)AlT + aBase;

    for (int it = 0; it < ITERS; ++it) {
        const bool dov  = (it < ITERS - 1);
        const bool seed = dov && (it < SEEDS);
        const short8* bv8 = (const short8*)Vh + (size_t)it * slab8 + wBase;
        const short8* bW8 = (const short8*)Wh + (size_t)it * slab8 + wBase;

        f32x4 aV0 = {0,0,0,0}, aV1 = {0,0,0,0}, aSa = {0,0,0,0};
        f32x4 aW0 = {0,0,0,0}, aW1 = {0,0,0,0};
        #pragma unroll
        for (int h = 0; h < 2; ++h) {
            short8 rT[8], rB[8], rW[8], rC[8], rS[8];
            #pragma unroll
            for (int i = 0; i < 8; ++i) {
                const int o = (h * 8 + i) * 4;
                rW[i] = aW8[o];
                rC[i] = bW8[o];
                if (dov)  { rT[i] = aT8[o]; rB[i] = bv8[o]; }
                if (seed) { rS[i] = aS8[o]; }
            }
            #pragma unroll
            for (int i = 0; i < 8; ++i) {
                if (i & 1) aW1 = __builtin_amdgcn_mfma_f32_16x16x32_bf16(rW[i], rC[i], aW1, 0, 0, 0);
                else       aW0 = __builtin_amdgcn_mfma_f32_16x16x32_bf16(rW[i], rC[i], aW0, 0, 0, 0);
                if (dov) {
                    if (i & 1) aV1 = __builtin_amdgcn_mfma_f32_16x16x32_bf16(rT[i], rB[i], aV1, 0, 0, 0);
                    else       aV0 = __builtin_amdgcn_mfma_f32_16x16x32_bf16(rT[i], rB[i], aV0, 0, 0, 0);
                    if (seed)  aSa = __builtin_amdgcn_mfma_f32_16x16x32_bf16(rS[i], rB[i], aSa, 0, 0, 0);
                }
            }
        }
        redW[wave * 64 + lane] = aW0 + aW1;
        if (dov) redV[wave * 64 + lane] = aV0 + aV1 + aSa; // AlT stream merged
        __syncthreads();
        if (tid < 256) {
            const int l = tid & 63, i2 = tid >> 6;
            const int col = l & 15;
            const int row = row0 + ((l >> 4) << 2) + i2;
            float w = 0.0f;
            #pragma unroll
            for (int wv = 0; wv < 8; ++wv) w += redW[wv * 64 + l][i2];
            Wf[(size_t)(it + 1) * SLAB + col * NDIM + row] = w;
            Wh[(size_t)(it + 1) * SLAB + col * NDIM + row] = __float2bfloat16(w);
            if (dov) {
                float v = 0.0f;
                #pragma unroll
                for (int wv = 0; wv < 8; ++wv) v += redV[wv * 64 + l][i2];
                float p = v + __shfl_xor(v, 1); // col0+col1 = A*(vh+vl), pairwise
                __hip_bfloat16* vo = Vh + (size_t)(it + 1) * SLAB;
                if (col == 0) {
                    __hip_bfloat16 hh = __float2bfloat16(p);
                    Vf[(size_t)(it + 1) * SLAB + row] = p;
                    vo[row] = hh;
                } else if (col == 1) {
                    __hip_bfloat16 hh = __float2bfloat16(p);
                    vo[NDIM + row] = __float2bfloat16(p - __bfloat162float(hh));
                } else {
                    vo[col * NDIM + row] = __float2bfloat16(0.0f);
                }
            }
        }
        grid.sync();
    }
}

// ---------- F_m = v_i . W_j  (i = min(m,31), j = m-i), fp32 ----------
__global__ __launch_bounds__(256) void k_fbatch(
        const float* __restrict__ Vf, const float* __restrict__ Wf,
        float* __restrict__ F) {
    const int m = blockIdx.x;
    const int i = (m < ITERS - 1) ? m : (ITERS - 1);
    const int j = m - i;
    const float* v = Vf + (size_t)i * SLAB; // col 0 = v_i
    const float* W = Wf + (size_t)j * SLAB;
    const int tid = threadIdx.x, lane = tid & 63, wave = tid >> 6;
    float acc[NC] = {};
    for (int k = tid; k < NDIM; k += 256) {
        float vk = v[k];
        #pragma unroll
        for (int c = 0; c < NC; ++c) acc[c] += vk * W[c * NDIM + k];
    }
    __shared__ float red[4][NC];
    #pragma unroll
    for (int c = 0; c < NC; ++c) {
        float s = acc[c];
        #pragma unroll
        for (int off = 32; off > 0; off >>= 1) s += __shfl_down(s, off);
        if (lane == 0) red[wave][c] = s;
    }
    __syncthreads();
    if (tid < NC) F[m * NC + tid] = red[0][tid] + red[1][tid] + red[2][tid] + red[3][tid];
}

// ---------- causal convolution + tanh epilogue ----------
__global__ __launch_bounds__(256) void k_conv(
        const float* __restrict__ F, const float* __restrict__ u,
        const float* __restrict__ yobs, const float* __restrict__ Dm,
        float* __restrict__ out) {
    __shared__ float Fl[JT * NC];
    __shared__ float zw[(JT + 256) * 9];
    const int tid = threadIdx.x;
    const int t0  = blockIdx.x * 256;
    for (int idx = tid; idx < JT * NC; idx += 256) Fl[idx] = F[idx];
    for (int idx = tid; idx < (JT + 256) * 9; idx += 256) {
        int k = idx / 9, c = idx - k * 9;
        int s = t0 - JT + k;
        float v = 0.0f;
        if (s >= 0 && s < NDIM) v = (c < 8) ? u[c * NDIM + s] : yobs[s];
        zw[idx] = v;
    }
    __syncthreads();
    const int t = t0 + tid;
    float y = (t < JT) ? Fl[t * NC + 9] : 0.0f; // C A'^t h0 term (truncated)
    #pragma unroll
    for (int c = 0; c < 8; ++c) y += Dm[c] * u[c * NDIM + t];
    for (int j = 0; j < JT; ++j) { // s = t-1-j; s<0 hits zero pad
        const float* fj = Fl + j * NC;
        const float* zz = zw + (tid + JT - 1 - j) * 9;
        float p = 0.0f;
        #pragma unroll
        for (int c = 0; c < 9; ++c) p += fj[c] * zz[c];
        y += p;
    }
    out[t] = 3.0f * tanhf(y);
}

extern "C" void kernel_launch(void* const* d_in, const int* in_sizes, int n_in,
                              void* d_out, int out_size, void* d_ws, size_t ws_size,
                              hipStream_t stream) {
    const float* u    = (const float*)d_in[0];
    const float* yobs = (const float*)d_in[1];
    const float* A    = (const float*)d_in[2];
    const float* Bm   = (const float*)d_in[3];
    const float* C    = (const float*)d_in[4];
    const float* Dm   = (const float*)d_in[5];
    const float* L    = (const float*)d_in[6];
    float* out = (float*)d_out;

    // workspace layout (~127 MB)
    char* ws = (char*)d_ws;
    __hip_bfloat16* Ah  = (__hip_bfloat16*)ws;                       // 32 MB
    __hip_bfloat16* AhT = (__hip_bfloat16*)(ws + 33554432ull);       // 32 MB
    __hip_bfloat16* AlT = (__hip_bfloat16*)(ws + 67108864ull);       // 32 MB
    __hip_bfloat16* Wh  = (__hip_bfloat16*)(ws + 100663296ull);      // 33*128 KB
    float*          Wf  = (float*)(ws + 104988672ull);               // 33*256 KB
    __hip_bfloat16* Vh  = (__hip_bfloat16*)(ws + 113639424ull);      // 32*128 KB
    float*          Vf  = (float*)(ws + 117833728ull);               // 32*256 KB
    float*          F   = (float*)(ws + 126222336ull);               // 2.56 KB

    k_build_a<<<dim3(4096), dim3(256), 0, stream>>>(A, C, L, Ah, AhT, AlT);
    k_build_w0<<<dim3(16), dim3(256), 0, stream>>>(Bm, Dm, L, Wf, Wh);
    k_build_v0<<<dim3(16), dim3(256), 0, stream>>>(C, Vf, Vh);

    {
        const __hip_bfloat16 *pAh = Ah, *pAhT = AhT, *pAlT = AlT;
        __hip_bfloat16 *pWh = Wh, *pVh = Vh;
        float *pWf = Wf, *pVf = Vf;
        void* args[] = {&pAh, &pAhT, &pAlT, &pWh, &pWf, &pVh, &pVf};
        hipLaunchCooperativeKernel((const void*)k_chain, dim3(256), dim3(512),
                                   args, 0, stream);
    }

    k_fbatch<<<dim3(JT), dim3(256), 0, stream>>>(Vf, Wf, F);
    k_conv<<<dim3(16), dim3(256), 0, stream>>>(F, u, yobs, Dm, out);
}

// Round 5
// 742.671 us; speedup vs baseline: 2.1783x; 2.1001x over previous
//
#include <hip/hip_runtime.h>
#include <hip/hip_bf16.h>
#include <math.h>

// Observer recurrence -> LTI Markov-parameter convolution, meet-in-the-middle.
//   A' = A - L*C, K = [B - L*D | L | h0]
//   f_m = C A'^m K = (A'^T^i C^T) . (A'^j K),  i = min(m,31), j = m - i
// v-chain packs v_hi (plane 0) and v_lo (plane 1) in one B operand; seeds
// (it<12) add an AlT*[vh|vl] correction stream (merged in reduction).
// Round-5 change vs round-4: cooperative kernel REMOVED. grid.sync on 8
// non-coherent XCDs measured ~35us/iter (round2 same step standalone = 11us,
// round3/4 in-coop = 45us). Now: 32 regular launches, each advancing BOTH
// chains (blocks 0-255 = W-step, 256-511 = v-step). Math identical to round 4.

constexpr int NDIM  = 4096;
constexpr int NC    = 10;         // live columns of K/W
constexpr int SLAB  = 16 * 4096;  // padded 16-col col-major slab (elements)
constexpr int JT    = 64;         // truncation length
constexpr int SEEDS = 12;         // AlT-corrected seed steps (v-chain)
constexpr int ITERS = 32;         // chain iterations

typedef float f32x4  __attribute__((ext_vector_type(4)));
typedef short short8 __attribute__((ext_vector_type(8)));

// ---------- build A' hi (row-major) + A'^T hi/lo (tiled transpose) ----------
__global__ __launch_bounds__(256) void k_build_a(
        const float* __restrict__ A, const float* __restrict__ C,
        const float* __restrict__ L,
        __hip_bfloat16* __restrict__ Ah, __hip_bfloat16* __restrict__ AhT,
        __hip_bfloat16* __restrict__ AlT) {
    __shared__ unsigned short hiT[64][68];
    __shared__ unsigned short loT[64][68];
    const int bi = blockIdx.x >> 6, bj = blockIdx.x & 63;
    const int i0 = bi << 6, j0 = bj << 6;
    const int r  = threadIdx.x >> 4;
    const int c4 = (threadIdx.x & 15) << 2;
    #pragma unroll
    for (int p = 0; p < 4; ++p) {
        const int il = r + (p << 4);
        const int i  = i0 + il;
        const float4 a = *(const float4*)(A + (size_t)i * NDIM + j0 + c4);
        const float Li = L[i];
        float v[4] = { a.x - Li * C[j0 + c4 + 0], a.y - Li * C[j0 + c4 + 1],
                       a.z - Li * C[j0 + c4 + 2], a.w - Li * C[j0 + c4 + 3] };
        union { ushort4 u4; __hip_bfloat16 h[4]; } hi, lo;
        #pragma unroll
        for (int s = 0; s < 4; ++s) {
            hi.h[s] = __float2bfloat16(v[s]);
            lo.h[s] = __float2bfloat16(v[s] - __bfloat162float(hi.h[s]));
        }
        *(ushort4*)((unsigned short*)Ah + (size_t)i * NDIM + j0 + c4) = hi.u4;
        #pragma unroll
        for (int s = 0; s < 4; ++s) {
            hiT[c4 + s][il] = ((unsigned short*)&hi.u4)[s];
            loT[c4 + s][il] = ((unsigned short*)&lo.u4)[s];
        }
    }
    __syncthreads();
    #pragma unroll
    for (int p = 0; p < 4; ++p) {
        const int jl = r + (p << 4);
        ushort4 h = *(ushort4*)&hiT[jl][c4];
        ushort4 l = *(ushort4*)&loT[jl][c4];
        *(ushort4*)((unsigned short*)AhT + (size_t)(j0 + jl) * NDIM + i0 + c4) = h;
        *(ushort4*)((unsigned short*)AlT + (size_t)(j0 + jl) * NDIM + i0 + c4) = l;
    }
}

// ---------- W0 = K (10 cols) and v0 = [hi(C^T)|lo(C^T)], one launch ----------
__global__ __launch_bounds__(256) void k_build_x0(
        const float* __restrict__ Bm, const float* __restrict__ Dm,
        const float* __restrict__ L, const float* __restrict__ C,
        float* __restrict__ Wf, __hip_bfloat16* __restrict__ Wh,
        float* __restrict__ Vf, __hip_bfloat16* __restrict__ Vh) {
    int k = blockIdx.x * blockDim.x + threadIdx.x; // < 4096
    float Lk = L[k];
    float col[16];
    #pragma unroll
    for (int c = 0; c < 8; ++c) col[c] = Bm[k * 8 + c] - Lk * Dm[c];
    col[8] = Lk; col[9] = 1.0f;
    #pragma unroll
    for (int c = 10; c < 16; ++c) col[c] = 0.0f;
    #pragma unroll
    for (int c = 0; c < 16; ++c) {
        Wf[c * NDIM + k] = col[c];
        Wh[c * NDIM + k] = __float2bfloat16(col[c]);
    }
    float c0 = C[k];
    __hip_bfloat16 h = __float2bfloat16(c0);
    Vf[k] = c0;
    Vh[k] = h;
    Vh[NDIM + k] = __float2bfloat16(c0 - __bfloat162float(h));
    #pragma unroll
    for (int p = 2; p < 16; ++p) Vh[p * NDIM + k] = __float2bfloat16(0.0f);
}

// ---------- one dual-chain step: blocks 0-255 W-step, 256-511 v-step ----------
// A-frag: lane = m + 16q holds M[row m][k=q*8+j]; B-frag col n = lane&15 reads
// plane n. D: col = lane&15, row = (lane>>4)*4 + i (validated rounds 2-4).
template <bool SEED>
__global__ __launch_bounds__(512, 4) void k_step2(
        const __hip_bfloat16* __restrict__ Ah, const __hip_bfloat16* __restrict__ AhT,
        const __hip_bfloat16* __restrict__ AlT,
        const __hip_bfloat16* __restrict__ WhIn, const __hip_bfloat16* __restrict__ VhIn,
        float* __restrict__ WfOut, __hip_bfloat16* __restrict__ WhOut,
        float* __restrict__ VfOut, __hip_bfloat16* __restrict__ VhOut) {
    __shared__ f32x4 red[512];
    const int tid  = threadIdx.x;
    const int lane = tid & 63, wave = tid >> 6;
    const int mr   = lane & 15, q = lane >> 4;
    const bool isV = (blockIdx.x >= 256);
    const int row0 = (blockIdx.x & 255) * 16;
    const size_t aBase = (((size_t)(row0 + mr) * NDIM + wave * 512) >> 3) + q;
    const size_t wBase = (((size_t)mr * NDIM + wave * 512) >> 3) + q;
    const short8* a8 = (const short8*)(isV ? AhT : Ah) + aBase;
    const short8* b8 = (const short8*)(isV ? VhIn : WhIn) + wBase;

    f32x4 acc0 = {0,0,0,0}, acc1 = {0,0,0,0}, accS = {0,0,0,0};
    if (SEED && isV) {
        // 3-stream seed path: 4-frag batches to stay under 128 VGPRs
        const short8* s8 = (const short8*)AlT + aBase;
        #pragma unroll
        for (int h = 0; h < 4; ++h) {
            short8 ra[4], rb[4], rs[4];
            #pragma unroll
            for (int i = 0; i < 4; ++i) {
                const int o = (h * 4 + i) * 4;
                ra[i] = a8[o]; rb[i] = b8[o]; rs[i] = s8[o];
            }
            #pragma unroll
            for (int i = 0; i < 4; ++i) {
                if (i & 1) acc1 = __builtin_amdgcn_mfma_f32_16x16x32_bf16(ra[i], rb[i], acc1, 0, 0, 0);
                else       acc0 = __builtin_amdgcn_mfma_f32_16x16x32_bf16(ra[i], rb[i], acc0, 0, 0, 0);
                accS = __builtin_amdgcn_mfma_f32_16x16x32_bf16(rs[i], rb[i], accS, 0, 0, 0);
            }
        }
    } else {
        // 2-stream path: 8-frag batches for MLP
        #pragma unroll
        for (int h = 0; h < 2; ++h) {
            short8 ra[8], rb[8];
            #pragma unroll
            for (int i = 0; i < 8; ++i) {
                const int o = (h * 8 + i) * 4;
                ra[i] = a8[o]; rb[i] = b8[o];
            }
            #pragma unroll
            for (int i = 0; i < 8; ++i) {
                if (i & 1) acc1 = __builtin_amdgcn_mfma_f32_16x16x32_bf16(ra[i], rb[i], acc1, 0, 0, 0);
                else       acc0 = __builtin_amdgcn_mfma_f32_16x16x32_bf16(ra[i], rb[i], acc0, 0, 0, 0);
            }
        }
    }
    red[wave * 64 + lane] = acc0 + acc1 + accS;
    __syncthreads();
    if (tid < 256) {
        const int l = tid & 63, i2 = tid >> 6;
        float v = 0.0f;
        #pragma unroll
        for (int wv = 0; wv < 8; ++wv) v += red[wv * 64 + l][i2];
        const int col = l & 15;
        const int row = row0 + ((l >> 4) << 2) + i2;
        if (!isV) {
            WfOut[col * NDIM + row] = v;
            WhOut[col * NDIM + row] = __float2bfloat16(v);
        } else {
            float p = v + __shfl_xor(v, 1); // col0+col1 = A'^T*(vh+vl)
            if (col == 0) {
                VfOut[row] = p;
                VhOut[row] = __float2bfloat16(p);
            } else if (col == 1) {
                __hip_bfloat16 hh = __float2bfloat16(p);
                VhOut[NDIM + row] = __float2bfloat16(p - __bfloat162float(hh));
            } else {
                VhOut[col * NDIM + row] = __float2bfloat16(0.0f);
            }
        }
    }
}

// ---------- F_m = v_i . W_j  (i = min(m,31), j = m-i), fp32 ----------
__global__ __launch_bounds__(256) void k_fbatch(
        const float* __restrict__ Vf, const float* __restrict__ Wf,
        float* __restrict__ F) {
    const int m = blockIdx.x;
    const int i = (m < ITERS - 1) ? m : (ITERS - 1);
    const int j = m - i;
    const float* v = Vf + (size_t)i * SLAB; // col 0 = v_i
    const float* W = Wf + (size_t)j * SLAB;
    const int tid = threadIdx.x, lane = tid & 63, wave = tid >> 6;
    float acc[NC] = {};
    for (int k = tid; k < NDIM; k += 256) {
        float vk = v[k];
        #pragma unroll
        for (int c = 0; c < NC; ++c) acc[c] += vk * W[c * NDIM + k];
    }
    __shared__ float red[4][NC];
    #pragma unroll
    for (int c = 0; c < NC; ++c) {
        float s = acc[c];
        #pragma unroll
        for (int off = 32; off > 0; off >>= 1) s += __shfl_down(s, off);
        if (lane == 0) red[wave][c] = s;
    }
    __syncthreads();
    if (tid < NC) F[m * NC + tid] = red[0][tid] + red[1][tid] + red[2][tid] + red[3][tid];
}

// ---------- causal convolution + tanh epilogue ----------
__global__ __launch_bounds__(256) void k_conv(
        const float* __restrict__ F, const float* __restrict__ u,
        const float* __restrict__ yobs, const float* __restrict__ Dm,
        float* __restrict__ out) {
    __shared__ float Fl[JT * NC];
    __shared__ float zw[(JT + 256) * 9];
    const int tid = threadIdx.x;
    const int t0  = blockIdx.x * 256;
    for (int idx = tid; idx < JT * NC; idx += 256) Fl[idx] = F[idx];
    for (int idx = tid; idx < (JT + 256) * 9; idx += 256) {
        int k = idx / 9, c = idx - k * 9;
        int s = t0 - JT + k;
        float v = 0.0f;
        if (s >= 0 && s < NDIM) v = (c < 8) ? u[c * NDIM + s] : yobs[s];
        zw[idx] = v;
    }
    __syncthreads();
    const int t = t0 + tid;
    float y = (t < JT) ? Fl[t * NC + 9] : 0.0f; // C A'^t h0 term (truncated)
    #pragma unroll
    for (int c = 0; c < 8; ++c) y += Dm[c] * u[c * NDIM + t];
    for (int j = 0; j < JT; ++j) { // s = t-1-j; s<0 hits zero pad
        const float* fj = Fl + j * NC;
        const float* zz = zw + (tid + JT - 1 - j) * 9;
        float p = 0.0f;
        #pragma unroll
        for (int c = 0; c < 9; ++c) p += fj[c] * zz[c];
        y += p;
    }
    out[t] = 3.0f * tanhf(y);
}

extern "C" void kernel_launch(void* const* d_in, const int* in_sizes, int n_in,
                              void* d_out, int out_size, void* d_ws, size_t ws_size,
                              hipStream_t stream) {
    const float* u    = (const float*)d_in[0];
    const float* yobs = (const float*)d_in[1];
    const float* A    = (const float*)d_in[2];
    const float* Bm   = (const float*)d_in[3];
    const float* C    = (const float*)d_in[4];
    const float* Dm   = (const float*)d_in[5];
    const float* L    = (const float*)d_in[6];
    float* out = (float*)d_out;

    // workspace layout (~127 MB)
    char* ws = (char*)d_ws;
    __hip_bfloat16* Ah  = (__hip_bfloat16*)ws;                       // 32 MB
    __hip_bfloat16* AhT = (__hip_bfloat16*)(ws + 33554432ull);       // 32 MB
    __hip_bfloat16* AlT = (__hip_bfloat16*)(ws + 67108864ull);       // 32 MB
    __hip_bfloat16* Wh  = (__hip_bfloat16*)(ws + 100663296ull);      // 33*128 KB
    float*          Wf  = (float*)(ws + 104988672ull);               // 33*256 KB
    __hip_bfloat16* Vh  = (__hip_bfloat16*)(ws + 113639424ull);      // 33*128 KB
    float*          Vf  = (float*)(ws + 117964800ull);               // 33*256 KB
    float*          F   = (float*)(ws + 126615552ull);               // 2.56 KB

    k_build_a<<<dim3(4096), dim3(256), 0, stream>>>(A, C, L, Ah, AhT, AlT);
    k_build_x0<<<dim3(16), dim3(256), 0, stream>>>(Bm, Dm, L, C, Wf, Wh, Vf, Vh);

    for (int it = 0; it < ITERS; ++it) {
        const size_t in  = (size_t)it * SLAB;
        const size_t out_ = (size_t)(it + 1) * SLAB;
        if (it < SEEDS)
            k_step2<true><<<dim3(512), dim3(512), 0, stream>>>(
                Ah, AhT, AlT, Wh + in, Vh + in,
                Wf + out_, Wh + out_, Vf + out_, Vh + out_);
        else
            k_step2<false><<<dim3(512), dim3(512), 0, stream>>>(
                Ah, AhT, AlT, Wh + in, Vh + in,
                Wf + out_, Wh + out_, Vf + out_, Vh + out_);
    }

    k_fbatch<<<dim3(JT), dim3(256), 0, stream>>>(Vf, Wf, F);
    k_conv<<<dim3(16), dim3(256), 0, stream>>>(F, u, yobs, Dm, out);
}

// Round 6
// 686.124 us; speedup vs baseline: 2.3578x; 1.0824x over previous
//
#include <hip/hip_runtime.h>
#include <hip/hip_bf16.h>
#include <math.h>

// Observer recurrence -> LTI Markov-parameter convolution, meet-in-the-middle.
//   A' = A - L*C, K = [B - L*D | L | h0]
//   f_m = C A'^m K = (A'^T^i C^T) . (A'^j K),  i = min(m,27), j = m - i
// v-chain packs v_hi (plane 0) and v_lo (plane 1) in one B operand; seeds
// (it<6) add an AlT*[vh|vl] correction stream (merged in reduction).
// Round-6 changes vs round-5:
//   * ITERS 32->28 (JT 64->56): truncation +~0.009 absmax, saves 4 quanta.
//   * SEEDS 12->6: bf16 noise enters at 0.9^6 terms (~2e-3), cheaper seeds.
//   * step shape: 256-thr blocks, 2 tiles/block, k-split 2, 16-iter load loop
//     (r1-style streaming) at 1 block/CU — tests latency-vs-fabric hypothesis;
//     per-CU rate was shape-invariant ~16 GB/s across r1/r2/r5.

constexpr int NDIM  = 4096;
constexpr int NC    = 10;         // live columns of K/W
constexpr int SLAB  = 16 * 4096;  // padded 16-col col-major slab (elements)
constexpr int JT    = 56;         // truncation length
constexpr int SEEDS = 6;          // AlT-corrected seed steps (v-chain)
constexpr int ITERS = 28;         // chain iterations

typedef float f32x4  __attribute__((ext_vector_type(4)));
typedef short short8 __attribute__((ext_vector_type(8)));

// ---------- build A' hi (row-major) + A'^T hi/lo (tiled transpose) ----------
__global__ __launch_bounds__(256) void k_build_a(
        const float* __restrict__ A, const float* __restrict__ C,
        const float* __restrict__ L,
        __hip_bfloat16* __restrict__ Ah, __hip_bfloat16* __restrict__ AhT,
        __hip_bfloat16* __restrict__ AlT) {
    __shared__ unsigned short hiT[64][68];
    __shared__ unsigned short loT[64][68];
    const int bi = blockIdx.x >> 6, bj = blockIdx.x & 63;
    const int i0 = bi << 6, j0 = bj << 6;
    const int r  = threadIdx.x >> 4;
    const int c4 = (threadIdx.x & 15) << 2;
    #pragma unroll
    for (int p = 0; p < 4; ++p) {
        const int il = r + (p << 4);
        const int i  = i0 + il;
        const float4 a = *(const float4*)(A + (size_t)i * NDIM + j0 + c4);
        const float Li = L[i];
        float v[4] = { a.x - Li * C[j0 + c4 + 0], a.y - Li * C[j0 + c4 + 1],
                       a.z - Li * C[j0 + c4 + 2], a.w - Li * C[j0 + c4 + 3] };
        union { ushort4 u4; __hip_bfloat16 h[4]; } hi, lo;
        #pragma unroll
        for (int s = 0; s < 4; ++s) {
            hi.h[s] = __float2bfloat16(v[s]);
            lo.h[s] = __float2bfloat16(v[s] - __bfloat162float(hi.h[s]));
        }
        *(ushort4*)((unsigned short*)Ah + (size_t)i * NDIM + j0 + c4) = hi.u4;
        #pragma unroll
        for (int s = 0; s < 4; ++s) {
            hiT[c4 + s][il] = ((unsigned short*)&hi.u4)[s];
            loT[c4 + s][il] = ((unsigned short*)&lo.u4)[s];
        }
    }
    __syncthreads();
    #pragma unroll
    for (int p = 0; p < 4; ++p) {
        const int jl = r + (p << 4);
        ushort4 h = *(ushort4*)&hiT[jl][c4];
        ushort4 l = *(ushort4*)&loT[jl][c4];
        *(ushort4*)((unsigned short*)AhT + (size_t)(j0 + jl) * NDIM + i0 + c4) = h;
        *(ushort4*)((unsigned short*)AlT + (size_t)(j0 + jl) * NDIM + i0 + c4) = l;
    }
}

// ---------- W0 = K (10 cols) and v0 = [hi(C^T)|lo(C^T)], one launch ----------
__global__ __launch_bounds__(256) void k_build_x0(
        const float* __restrict__ Bm, const float* __restrict__ Dm,
        const float* __restrict__ L, const float* __restrict__ C,
        float* __restrict__ Wf, __hip_bfloat16* __restrict__ Wh,
        float* __restrict__ Vf, __hip_bfloat16* __restrict__ Vh) {
    int k = blockIdx.x * blockDim.x + threadIdx.x; // < 4096
    float Lk = L[k];
    float col[16];
    #pragma unroll
    for (int c = 0; c < 8; ++c) col[c] = Bm[k * 8 + c] - Lk * Dm[c];
    col[8] = Lk; col[9] = 1.0f;
    #pragma unroll
    for (int c = 10; c < 16; ++c) col[c] = 0.0f;
    #pragma unroll
    for (int c = 0; c < 16; ++c) {
        Wf[c * NDIM + k] = col[c];
        Wh[c * NDIM + k] = __float2bfloat16(col[c]);
    }
    float c0 = C[k];
    __hip_bfloat16 h = __float2bfloat16(c0);
    Vf[k] = c0;
    Vh[k] = h;
    Vh[NDIM + k] = __float2bfloat16(c0 - __bfloat162float(h));
    #pragma unroll
    for (int p = 2; p < 16; ++p) Vh[p * NDIM + k] = __float2bfloat16(0.0f);
}

// ---------- one dual-chain step ----------
// 256 blocks x 256 thr. Blocks 0-127 = W-step (Ah), 128-255 = v-step (AhT/AlT).
// Block owns 2 tiles of 16 rows; each tile split across 2 waves (k halves);
// wave loops 16x over (4 a-frags + 4 b-frags + 4 MFMAs) — streaming shape.
// A-frag: lane = m + 16q holds M[row m][k=q*8+j]; B-frag col n = lane&15.
// D: col = lane&15, row = (lane>>4)*4 + i (validated rounds 2-5).
template <bool SEED>
__global__ __launch_bounds__(256, 1) void k_step2(
        const __hip_bfloat16* __restrict__ Ah, const __hip_bfloat16* __restrict__ AhT,
        const __hip_bfloat16* __restrict__ AlT,
        const __hip_bfloat16* __restrict__ WhIn, const __hip_bfloat16* __restrict__ VhIn,
        float* __restrict__ WfOut, __hip_bfloat16* __restrict__ WhOut,
        float* __restrict__ VfOut, __hip_bfloat16* __restrict__ VhOut) {
    __shared__ f32x4 red[4][64];
    const int tid  = threadIdx.x;
    const int lane = tid & 63, wave = tid >> 6;
    const int tl   = wave >> 1;      // tile within block (0..1)
    const int kh   = wave & 1;       // k half (0..1)
    const bool isV = (blockIdx.x >= 128);
    const int bc   = blockIdx.x & 127;
    const int tile = bc * 2 + tl;    // 0..255
    const int row0 = tile * 16;
    const int mr   = lane & 15, q = lane >> 4;
    const int k0   = kh * 2048;
    const size_t aBase = (((size_t)(row0 + mr) * NDIM + k0) >> 3) + q;
    const size_t wBase = (((size_t)mr * NDIM + k0) >> 3) + q;
    const short8* a8 = (const short8*)(isV ? AhT : Ah) + aBase;
    const short8* b8 = (const short8*)(isV ? VhIn : WhIn) + wBase;

    f32x4 a0 = {0,0,0,0}, a1 = {0,0,0,0}, a2 = {0,0,0,0}, a3 = {0,0,0,0};
    f32x4 s0 = {0,0,0,0}, s1 = {0,0,0,0};
    if (SEED && isV) {
        const short8* sp8 = (const short8*)AlT + aBase;
        for (int it = 0; it < 16; ++it) {
            short8 ra[4], rb[4], rs[4];
            #pragma unroll
            for (int s = 0; s < 4; ++s) {
                const int o = it * 16 + s * 4;
                ra[s] = a8[o]; rb[s] = b8[o]; rs[s] = sp8[o];
            }
            a0 = __builtin_amdgcn_mfma_f32_16x16x32_bf16(ra[0], rb[0], a0, 0, 0, 0);
            a1 = __builtin_amdgcn_mfma_f32_16x16x32_bf16(ra[1], rb[1], a1, 0, 0, 0);
            a2 = __builtin_amdgcn_mfma_f32_16x16x32_bf16(ra[2], rb[2], a2, 0, 0, 0);
            a3 = __builtin_amdgcn_mfma_f32_16x16x32_bf16(ra[3], rb[3], a3, 0, 0, 0);
            s0 = __builtin_amdgcn_mfma_f32_16x16x32_bf16(rs[0], rb[0], s0, 0, 0, 0);
            s1 = __builtin_amdgcn_mfma_f32_16x16x32_bf16(rs[1], rb[1], s1, 0, 0, 0);
            s0 = __builtin_amdgcn_mfma_f32_16x16x32_bf16(rs[2], rb[2], s0, 0, 0, 0);
            s1 = __builtin_amdgcn_mfma_f32_16x16x32_bf16(rs[3], rb[3], s1, 0, 0, 0);
        }
    } else {
        for (int it = 0; it < 16; ++it) {
            short8 ra[4], rb[4];
            #pragma unroll
            for (int s = 0; s < 4; ++s) {
                const int o = it * 16 + s * 4;
                ra[s] = a8[o]; rb[s] = b8[o];
            }
            a0 = __builtin_amdgcn_mfma_f32_16x16x32_bf16(ra[0], rb[0], a0, 0, 0, 0);
            a1 = __builtin_amdgcn_mfma_f32_16x16x32_bf16(ra[1], rb[1], a1, 0, 0, 0);
            a2 = __builtin_amdgcn_mfma_f32_16x16x32_bf16(ra[2], rb[2], a2, 0, 0, 0);
            a3 = __builtin_amdgcn_mfma_f32_16x16x32_bf16(ra[3], rb[3], a3, 0, 0, 0);
        }
    }
    red[wave][lane] = a0 + a1 + a2 + a3 + s0 + s1;
    __syncthreads();
    if (tid < 128) {
        const int t2 = tid >> 6, l = tid & 63;
        f32x4 v = red[t2 * 2][l] + red[t2 * 2 + 1][l];
        const int col = l & 15;
        const int rb0 = (bc * 2 + t2) * 16 + ((l >> 4) << 2);
        if (!isV) {
            #pragma unroll
            for (int i = 0; i < 4; ++i) {
                WfOut[col * NDIM + rb0 + i] = v[i];
                WhOut[col * NDIM + rb0 + i] = __float2bfloat16(v[i]);
            }
        } else {
            #pragma unroll
            for (int i = 0; i < 4; ++i) {
                float p = v[i] + __shfl_xor(v[i], 1); // col0+col1 = A'^T*(vh+vl)
                if (col == 0) {
                    VfOut[rb0 + i] = p;
                    VhOut[rb0 + i] = __float2bfloat16(p);
                } else if (col == 1) {
                    __hip_bfloat16 hh = __float2bfloat16(p);
                    VhOut[NDIM + rb0 + i] = __float2bfloat16(p - __bfloat162float(hh));
                } else {
                    VhOut[col * NDIM + rb0 + i] = __float2bfloat16(0.0f);
                }
            }
        }
    }
}

// ---------- F_m = v_i . W_j  (i = min(m,ITERS-1), j = m-i), fp32 ----------
__global__ __launch_bounds__(256) void k_fbatch(
        const float* __restrict__ Vf, const float* __restrict__ Wf,
        float* __restrict__ F) {
    const int m = blockIdx.x;
    const int i = (m < ITERS - 1) ? m : (ITERS - 1);
    const int j = m - i;
    const float* v = Vf + (size_t)i * SLAB; // col 0 = v_i
    const float* W = Wf + (size_t)j * SLAB;
    const int tid = threadIdx.x, lane = tid & 63, wave = tid >> 6;
    float acc[NC] = {};
    for (int k = tid; k < NDIM; k += 256) {
        float vk = v[k];
        #pragma unroll
        for (int c = 0; c < NC; ++c) acc[c] += vk * W[c * NDIM + k];
    }
    __shared__ float red[4][NC];
    #pragma unroll
    for (int c = 0; c < NC; ++c) {
        float s = acc[c];
        #pragma unroll
        for (int off = 32; off > 0; off >>= 1) s += __shfl_down(s, off);
        if (lane == 0) red[wave][c] = s;
    }
    __syncthreads();
    if (tid < NC) F[m * NC + tid] = red[0][tid] + red[1][tid] + red[2][tid] + red[3][tid];
}

// ---------- causal convolution + tanh epilogue ----------
__global__ __launch_bounds__(256) void k_conv(
        const float* __restrict__ F, const float* __restrict__ u,
        const float* __restrict__ yobs, const float* __restrict__ Dm,
        float* __restrict__ out) {
    __shared__ float Fl[JT * NC];
    __shared__ float zw[(JT + 256) * 9];
    const int tid = threadIdx.x;
    const int t0  = blockIdx.x * 256;
    for (int idx = tid; idx < JT * NC; idx += 256) Fl[idx] = F[idx];
    for (int idx = tid; idx < (JT + 256) * 9; idx += 256) {
        int k = idx / 9, c = idx - k * 9;
        int s = t0 - JT + k;
        float v = 0.0f;
        if (s >= 0 && s < NDIM) v = (c < 8) ? u[c * NDIM + s] : yobs[s];
        zw[idx] = v;
    }
    __syncthreads();
    const int t = t0 + tid;
    float y = (t < JT) ? Fl[t * NC + 9] : 0.0f; // C A'^t h0 term (truncated)
    #pragma unroll
    for (int c = 0; c < 8; ++c) y += Dm[c] * u[c * NDIM + t];
    for (int j = 0; j < JT; ++j) { // s = t-1-j; s<0 hits zero pad
        const float* fj = Fl + j * NC;
        const float* zz = zw + (tid + JT - 1 - j) * 9;
        float p = 0.0f;
        #pragma unroll
        for (int c = 0; c < 9; ++c) p += fj[c] * zz[c];
        y += p;
    }
    out[t] = 3.0f * tanhf(y);
}

extern "C" void kernel_launch(void* const* d_in, const int* in_sizes, int n_in,
                              void* d_out, int out_size, void* d_ws, size_t ws_size,
                              hipStream_t stream) {
    const float* u    = (const float*)d_in[0];
    const float* yobs = (const float*)d_in[1];
    const float* A    = (const float*)d_in[2];
    const float* Bm   = (const float*)d_in[3];
    const float* C    = (const float*)d_in[4];
    const float* Dm   = (const float*)d_in[5];
    const float* L    = (const float*)d_in[6];
    float* out = (float*)d_out;

    // workspace layout (~127 MB)
    char* ws = (char*)d_ws;
    __hip_bfloat16* Ah  = (__hip_bfloat16*)ws;                       // 32 MB
    __hip_bfloat16* AhT = (__hip_bfloat16*)(ws + 33554432ull);       // 32 MB
    __hip_bfloat16* AlT = (__hip_bfloat16*)(ws + 67108864ull);       // 32 MB
    __hip_bfloat16* Wh  = (__hip_bfloat16*)(ws + 100663296ull);      // <=33*128 KB
    float*          Wf  = (float*)(ws + 104988672ull);               // <=33*256 KB
    __hip_bfloat16* Vh  = (__hip_bfloat16*)(ws + 113639424ull);      // <=33*128 KB
    float*          Vf  = (float*)(ws + 117964800ull);               // <=33*256 KB
    float*          F   = (float*)(ws + 126615552ull);               // 2.24 KB

    k_build_a<<<dim3(4096), dim3(256), 0, stream>>>(A, C, L, Ah, AhT, AlT);
    k_build_x0<<<dim3(16), dim3(256), 0, stream>>>(Bm, Dm, L, C, Wf, Wh, Vf, Vh);

    for (int it = 0; it < ITERS; ++it) {
        const size_t in  = (size_t)it * SLAB;
        const size_t out_ = (size_t)(it + 1) * SLAB;
        if (it < SEEDS)
            k_step2<true><<<dim3(256), dim3(256), 0, stream>>>(
                Ah, AhT, AlT, Wh + in, Vh + in,
                Wf + out_, Wh + out_, Vf + out_, Vh + out_);
        else
            k_step2<false><<<dim3(256), dim3(256), 0, stream>>>(
                Ah, AhT, AlT, Wh + in, Vh + in,
                Wf + out_, Wh + out_, Vf + out_, Vh + out_);
    }

    k_fbatch<<<dim3(JT), dim3(256), 0, stream>>>(Vf, Wf, F);
    k_conv<<<dim3(16), dim3(256), 0, stream>>>(F, u, yobs, Dm, out);
}